// Round 11
// baseline (40.302 us; speedup 1.0000x reference)
//
#include <hip/hip_runtime.h>

#define HADN 4096
#define NFEAT 2048
#define INV2PI 0.15915494309189535f

typedef float floatx4 __attribute__((ext_vector_type(4)));
typedef const __attribute__((address_space(1))) void* gas_cptr;
typedef __attribute__((address_space(3))) void* las_ptr;

// Async global->LDS DMA, 16B per lane. Address-space casts via integer
// round-trip. LDS dest must be wave-uniform base + lane*16 (ours is).
__device__ __forceinline__ void gload_lds16(const float* g, float* l) {
  __builtin_amdgcn_global_load_lds(
      (gas_cptr)(unsigned long long)g,
      (las_ptr)(unsigned)(unsigned long long)l, 16, 0, 0);
}

// out-bit <- in-axis mapping of one reference "fwht" (derived by axis tracking):
// bit0<-a6, bit1<-H(a3), bit2<-a7, bit3<-a0, bit4<-a8, bit5<-H(a4),
// bit6<-a9, bit7<-a2, bit8<-a10, bit9<-H(a5), bit10<-a11, bit11<-H(a1)
__device__ __forceinline__ int pi_map(int q) {
  return  (((q >> 3) & 1))
        | (((q >> 11) & 1) << 1)
        | (((q >> 7) & 1) << 2)
        | (((q >> 1) & 1) << 3)
        | (((q >> 5) & 1) << 4)
        | (((q >> 9) & 1) << 5)
        | (((q >> 0) & 1) << 6)
        | (((q >> 2) & 1) << 7)
        | (((q >> 4) & 1) << 8)
        | (((q >> 6) & 1) << 9)
        | (((q >> 8) & 1) << 10)
        | (((q >> 10) & 1) << 11);
}

__device__ __forceinline__ int pi_inv_map(int p) {
  return  (((p >> 6) & 1))
        | (((p >> 3) & 1) << 1)
        | (((p >> 7) & 1) << 2)
        | (((p >> 0) & 1) << 3)
        | (((p >> 8) & 1) << 4)
        | (((p >> 4) & 1) << 5)
        | (((p >> 9) & 1) << 6)
        | (((p >> 2) & 1) << 7)
        | (((p >> 10) & 1) << 8)
        | (((p >> 5) & 1) << 9)
        | (((p >> 11) & 1) << 10)
        | (((p >> 1) & 1) << 11);
}

// LDS bank swizzle: XOR bits {6,7,8}^{9,10,11} into bits {2,3,4}.
// Intra-128B-line permutation -> pre-swizzling the GLOBAL source keeps
// full-line coalescing per DMA instruction while LDS dest stays linear.
__device__ __forceinline__ int swz(int p) {
  return p ^ ((((p >> 6) ^ (p >> 9)) & 7) << 2);
}

template <int BIT>
__device__ __forceinline__ void bfly(float* r) {
#pragma unroll
  for (int e = 0; e < 16; ++e) {
    if ((e & BIT) == 0) {
      const int f = e | BIT;
      const float a = r[e], b = r[f];
      r[e] = a + b;
      r[f] = a - b;
    }
  }
}

// Cross-lane butterfly via DPP quad-perm (VALU, not DS pipe).
// CTRL=0xB1 -> lane^1, CTRL=0x4E -> lane^2.
template <int CTRL>
__device__ __forceinline__ void dpp_bfly(float* r, bool upper) {
  const unsigned sm = upper ? 0x80000000u : 0u;
#pragma unroll
  for (int e = 0; e < 16; ++e) {
    const int pv = __builtin_amdgcn_update_dpp(
        0, __float_as_int(r[e]), CTRL, 0xF, 0xF, true);
    r[e] = __int_as_float(pv) + __int_as_float(__float_as_int(r[e]) ^ sm);
  }
}

__device__ __forceinline__ void frag_load(const float* L, int base, float* r) {
#pragma unroll
  for (int g = 0; g < 4; ++g) {         // g bits -> p-bits {3,4}
    const int p = base | ((g & 1) << 3) | (((g >> 1) & 1) << 4);
    const float4 v = *(const float4*)(L + swz(p));
    r[g * 4 + 0] = v.x; r[g * 4 + 1] = v.y; r[g * 4 + 2] = v.z; r[g * 4 + 3] = v.w;
  }
}

__device__ __forceinline__ void frag_store(float* L, int base, const float* r) {
#pragma unroll
  for (int g = 0; g < 4; ++g) {
    const int p = base | ((g & 1) << 3) | (((g >> 1) & 1) << 4);
    const float4 v = make_float4(r[g * 4 + 0], r[g * 4 + 1], r[g * 4 + 2], r[g * 4 + 3]);
    *(float4*)(L + swz(p)) = v;
  }
}

// Both fwhts + both sign applications, fully in-register.
__device__ __forceinline__ void frag_compute(float* r, unsigned sw1,
                                             unsigned sw2, int l) {
  // D1 signs (input space), packed 1 word/lane.
#pragma unroll
  for (int e = 0; e < 16; ++e) {
    const int pos = (e & 3) | ((e & 12) << 1);   // e0,e1->bits0,1; e2,e3->bits3,4
    r[e] = __int_as_float(__float_as_int(r[e]) ^ ((sw1 >> pos) << 31));
  }
  // fwht #1: Hadamard on p-bits {1,3,4,5}: e-bits {1,2,3} + lane-bit0
  bfly<2>(r); bfly<4>(r); bfly<8>(r);
  dpp_bfly<0xB1>(r, (l & 1) != 0);
  // D2 signs (z-space), packed 1 word/lane.
#pragma unroll
  for (int e = 0; e < 16; ++e) {
    const int pos = (e & 3) | ((e & 12) << 1);
    r[e] = __int_as_float(__float_as_int(r[e]) ^ ((sw2 >> pos) << 31));
  }
  // fwht #2: Hadamard on p-bits {0,3,4,8}: e-bits {0,2,3} + lane-bit1
  bfly<1>(r); bfly<4>(r); bfly<8>(r);
  dpp_bfly<0x4E>(r, (l & 2) != 0);
}

// Fully parallel setup: one thread per Hadamard index; sign packing via
// __ballot (64-bit mask; lanes 0 and 32 write the two 32-bit words).
__global__ __launch_bounds__(256) void srf_setup(
    const float* __restrict__ D1, const float* __restrict__ D2,
    const float* __restrict__ D3, const int* __restrict__ perm,
    const float* __restrict__ bias,
    unsigned* __restrict__ D1sgn, unsigned* __restrict__ D2sgn,
    float* __restrict__ dgc, int* __restrict__ gidx,
    float* __restrict__ bzc) {
  const int i = blockIdx.x * 256 + threadIdx.x;   // 0..4095 (16 blocks)
  const bool b1 = (__float_as_uint(D1[i]) >> 31) != 0;
  const bool b2 = (__float_as_uint(D2[pi_inv_map(i)]) >> 31) != 0;
  const unsigned long long m1 = __ballot(b1);
  const unsigned long long m2 = __ballot(b2);
  const int lane = i & 63;
  if ((lane & 31) == 0) {
    D1sgn[i >> 5] = (unsigned)(m1 >> (lane & 32));
    D2sgn[i >> 5] = (unsigned)(m2 >> (lane & 32));
  }
  if (i < NFEAT) {
    const int j = perm[i];
    gidx[i] = swz(pi_map(pi_map(j)));
    dgc[i] = 0.0625f * INV2PI * D3[j];
    bzc[i] = INV2PI * bias[i];
  }
}

// 256 threads, 2 rows per block, 2 rows per THREAD: each thread runs two
// independent 16-elem butterfly chains (2x VALU/DS ILP), tables and sign
// words amortized over both rows. Wave-local DMA + per-wave vmcnt wait.
// LDS 32KB -> 5 blocks x 4 waves = 20 waves/CU.
__global__ __launch_bounds__(256) void srf_main(
    const float* __restrict__ x,
    const unsigned* __restrict__ D1sgn, const unsigned* __restrict__ D2sgn,
    const float* __restrict__ dgc, const int* __restrict__ gidx,
    const float* __restrict__ bzc, float* __restrict__ out) {
  __shared__ float lds[2][HADN];        // 32 KiB
  const int tid = threadIdx.x;
  const long row = (long)blockIdx.x * 2;
  const int l = tid & 63;
  const int w = tid >> 6;               // wave -> p-bits {10,11}
  const int base = (((l >> 2) & 1) << 2) | ((l & 1) << 5) | (((l >> 3) & 1) << 6)
                 | (((l >> 4) & 1) << 7) | (((l >> 1) & 1) << 8)
                 | (((l >> 5) & 1) << 9) | (w << 10);

  // ---- Stage 1: async DMA both rows' wave-local regions, pre-swizzled src.
  const float* xr0 = x + row * HADN;
  const float* xr1 = xr0 + HADN;
#pragma unroll
  for (int k = 0; k < 4; ++k) {
    const int q = w * 1024 + k * 256 + l * 4;  // linear dest float index
    gload_lds16(xr0 + swz(q), &lds[0][q]);
  }
#pragma unroll
  for (int k = 0; k < 4; ++k) {
    const int q = w * 1024 + k * 256 + l * 4;
    gload_lds16(xr1 + swz(q), &lds[1][q]);
  }

  // Sign words + stage-3 tables (L2-resident), drain with the same wait.
  const unsigned sw1 = D1sgn[base >> 5] >> (base & 4);
  const unsigned sw2 = D2sgn[base >> 5] >> (base & 4);
  const int o0 = tid * 4;               // outputs 0..1023
  const int o1 = 1024 + tid * 4;        // outputs 1024..2047
  const int4   gi0 = *(const int4*)(gidx + o0);
  const float4 dg0 = *(const float4*)(dgc + o0);
  const float4 bz0 = *(const float4*)(bzc + o0);
  const int4   gi1 = *(const int4*)(gidx + o1);
  const float4 dg1 = *(const float4*)(dgc + o1);
  const float4 bz1 = *(const float4*)(bzc + o1);

  // Per-wave wait: this wave's DMAs + table loads done. No block barrier.
  asm volatile("s_waitcnt vmcnt(0)" ::: "memory");
  __builtin_amdgcn_sched_barrier(0);

  // ---- Stage 2: two independent chains (row 0 and row 1), loads batched
  //      before computes so the VALU work of both rows interleaves.
  float r0[16], r1[16];
  frag_load(&lds[0][0], base, r0);
  frag_load(&lds[1][0], base, r1);
  frag_compute(r0, sw1, sw2, l);
  frag_compute(r1, sw1, sw2, l);
  frag_store(&lds[0][0], base, r0);
  frag_store(&lds[1][0], base, r1);
  __syncthreads();  // only barrier: all waves' stage-2 visible to gather

  // ---- Stage 3: permuted gather, cos epilogue, coalesced nt float4 store.
  float* op = out + row * NFEAT;
  floatx4 a;
  a.x = 0.03125f * __builtin_amdgcn_cosf(fmaf(lds[0][gi0.x], dg0.x, bz0.x));
  a.y = 0.03125f * __builtin_amdgcn_cosf(fmaf(lds[0][gi0.y], dg0.y, bz0.y));
  a.z = 0.03125f * __builtin_amdgcn_cosf(fmaf(lds[0][gi0.z], dg0.z, bz0.z));
  a.w = 0.03125f * __builtin_amdgcn_cosf(fmaf(lds[0][gi0.w], dg0.w, bz0.w));
  __builtin_nontemporal_store(a, (floatx4*)(op + o0));
  floatx4 b;
  b.x = 0.03125f * __builtin_amdgcn_cosf(fmaf(lds[0][gi1.x], dg1.x, bz1.x));
  b.y = 0.03125f * __builtin_amdgcn_cosf(fmaf(lds[0][gi1.y], dg1.y, bz1.y));
  b.z = 0.03125f * __builtin_amdgcn_cosf(fmaf(lds[0][gi1.z], dg1.z, bz1.z));
  b.w = 0.03125f * __builtin_amdgcn_cosf(fmaf(lds[0][gi1.w], dg1.w, bz1.w));
  __builtin_nontemporal_store(b, (floatx4*)(op + o1));
  floatx4 c;
  c.x = 0.03125f * __builtin_amdgcn_cosf(fmaf(lds[1][gi0.x], dg0.x, bz0.x));
  c.y = 0.03125f * __builtin_amdgcn_cosf(fmaf(lds[1][gi0.y], dg0.y, bz0.y));
  c.z = 0.03125f * __builtin_amdgcn_cosf(fmaf(lds[1][gi0.z], dg0.z, bz0.z));
  c.w = 0.03125f * __builtin_amdgcn_cosf(fmaf(lds[1][gi0.w], dg0.w, bz0.w));
  __builtin_nontemporal_store(c, (floatx4*)(op + NFEAT + o0));
  floatx4 d;
  d.x = 0.03125f * __builtin_amdgcn_cosf(fmaf(lds[1][gi1.x], dg1.x, bz1.x));
  d.y = 0.03125f * __builtin_amdgcn_cosf(fmaf(lds[1][gi1.y], dg1.y, bz1.y));
  d.z = 0.03125f * __builtin_amdgcn_cosf(fmaf(lds[1][gi1.z], dg1.z, bz1.z));
  d.w = 0.03125f * __builtin_amdgcn_cosf(fmaf(lds[1][gi1.w], dg1.w, bz1.w));
  __builtin_nontemporal_store(d, (floatx4*)(op + NFEAT + o1));
}

extern "C" void kernel_launch(void* const* d_in, const int* in_sizes, int n_in,
                              void* d_out, int out_size, void* d_ws, size_t ws_size,
                              hipStream_t stream) {
  const float* x    = (const float*)d_in[0];
  const float* D1   = (const float*)d_in[1];
  const float* D2   = (const float*)d_in[2];
  const float* D3   = (const float*)d_in[3];
  const float* bias = (const float*)d_in[4];
  const int*   perm = (const int*)d_in[5];
  float* out = (float*)d_out;

  unsigned* D1sgn = (unsigned*)d_ws;        // 128 u32
  unsigned* D2sgn = D1sgn + 128;            // 128 u32
  float*    dgc   = (float*)(D2sgn + 128);  // 2048 f32
  int*      gidx  = (int*)(dgc + NFEAT);    // 2048 i32
  float*    bzc   = (float*)(gidx + NFEAT); // 2048 f32

  srf_setup<<<16, 256, 0, stream>>>(D1, D2, D3, perm, bias,
                                    D1sgn, D2sgn, dgc, gidx, bzc);
  srf_main<<<4096, 256, 0, stream>>>(x, D1sgn, D2sgn, dgc, gidx, bzc, out);
}

// Round 12
// 39.494 us; speedup vs baseline: 1.0205x; 1.0205x over previous
//
#include <hip/hip_runtime.h>

#define HADN 4096
#define NFEAT 2048
#define INV2PI 0.15915494309189535f

typedef float floatx4 __attribute__((ext_vector_type(4)));
typedef const __attribute__((address_space(1))) void* gas_cptr;
typedef __attribute__((address_space(3))) void* las_ptr;

// Async global->LDS DMA, 16B per lane. Address-space casts via integer
// round-trip. LDS dest must be wave-uniform base + lane*16 (ours is).
__device__ __forceinline__ void gload_lds16(const float* g, float* l) {
  __builtin_amdgcn_global_load_lds(
      (gas_cptr)(unsigned long long)g,
      (las_ptr)(unsigned)(unsigned long long)l, 16, 0, 0);
}

// out-bit <- in-axis mapping of one reference "fwht" (derived by axis tracking):
// bit0<-a6, bit1<-H(a3), bit2<-a7, bit3<-a0, bit4<-a8, bit5<-H(a4),
// bit6<-a9, bit7<-a2, bit8<-a10, bit9<-H(a5), bit10<-a11, bit11<-H(a1)
__device__ __forceinline__ int pi_map(int q) {
  return  (((q >> 3) & 1))
        | (((q >> 11) & 1) << 1)
        | (((q >> 7) & 1) << 2)
        | (((q >> 1) & 1) << 3)
        | (((q >> 5) & 1) << 4)
        | (((q >> 9) & 1) << 5)
        | (((q >> 0) & 1) << 6)
        | (((q >> 2) & 1) << 7)
        | (((q >> 4) & 1) << 8)
        | (((q >> 6) & 1) << 9)
        | (((q >> 8) & 1) << 10)
        | (((q >> 10) & 1) << 11);
}

__device__ __forceinline__ int pi_inv_map(int p) {
  return  (((p >> 6) & 1))
        | (((p >> 3) & 1) << 1)
        | (((p >> 7) & 1) << 2)
        | (((p >> 0) & 1) << 3)
        | (((p >> 8) & 1) << 4)
        | (((p >> 4) & 1) << 5)
        | (((p >> 9) & 1) << 6)
        | (((p >> 2) & 1) << 7)
        | (((p >> 10) & 1) << 8)
        | (((p >> 5) & 1) << 9)
        | (((p >> 11) & 1) << 10)
        | (((p >> 1) & 1) << 11);
}

// LDS bank swizzle: XOR bits {6,7,8}^{9,10,11} into bits {2,3,4}.
// Intra-128B-line permutation -> pre-swizzling the GLOBAL source keeps
// full-line coalescing per DMA instruction while LDS dest stays linear.
__device__ __forceinline__ int swz(int p) {
  return p ^ ((((p >> 6) ^ (p >> 9)) & 7) << 2);
}

template <int BIT>
__device__ __forceinline__ void bfly(float* r) {
#pragma unroll
  for (int e = 0; e < 16; ++e) {
    if ((e & BIT) == 0) {
      const int f = e | BIT;
      const float a = r[e], b = r[f];
      r[e] = a + b;
      r[f] = a - b;
    }
  }
}

// Cross-lane butterfly via DPP quad-perm (VALU, not DS pipe).
// CTRL=0xB1 -> lane^1, CTRL=0x4E -> lane^2.
template <int CTRL>
__device__ __forceinline__ void dpp_bfly(float* r, bool upper) {
  const unsigned sm = upper ? 0x80000000u : 0u;
#pragma unroll
  for (int e = 0; e < 16; ++e) {
    const int pv = __builtin_amdgcn_update_dpp(
        0, __float_as_int(r[e]), CTRL, 0xF, 0xF, true);
    r[e] = __int_as_float(pv) + __int_as_float(__float_as_int(r[e]) ^ sm);
  }
}

// Fully parallel setup: one thread per Hadamard index; sign packing via
// __ballot (64-bit mask; lanes 0 and 32 write the two 32-bit words).
__global__ __launch_bounds__(256) void srf_setup(
    const float* __restrict__ D1, const float* __restrict__ D2,
    const float* __restrict__ D3, const int* __restrict__ perm,
    const float* __restrict__ bias,
    unsigned* __restrict__ D1sgn, unsigned* __restrict__ D2sgn,
    float* __restrict__ dgc, int* __restrict__ gidx,
    float* __restrict__ bzc) {
  const int i = blockIdx.x * 256 + threadIdx.x;   // 0..4095 (16 blocks)
  const bool b1 = (__float_as_uint(D1[i]) >> 31) != 0;
  const bool b2 = (__float_as_uint(D2[pi_inv_map(i)]) >> 31) != 0;
  const unsigned long long m1 = __ballot(b1);
  const unsigned long long m2 = __ballot(b2);
  const int lane = i & 63;
  if ((lane & 31) == 0) {
    D1sgn[i >> 5] = (unsigned)(m1 >> (lane & 32));
    D2sgn[i >> 5] = (unsigned)(m2 >> (lane & 32));
  }
  if (i < NFEAT) {
    const int j = perm[i];
    gidx[i] = swz(pi_map(pi_map(j)));
    dgc[i] = 0.0625f * INV2PI * D3[j];
    bzc[i] = INV2PI * bias[i];
  }
}

// 512 threads, 2 rows per block (R10 structure, best = 39.6us). Wave-local
// DMA + per-wave vmcnt wait; single block barrier before the cross-wave
// gather. ONLY change vs R10: plain (cached) stores instead of nontemporal,
// so `out` (67 MB) can stay L3-resident across graph replays instead of
// forcing HBM write traffic every replay.
__global__ __launch_bounds__(512) void srf_main(
    const float* __restrict__ x,
    const unsigned* __restrict__ D1sgn, const unsigned* __restrict__ D2sgn,
    const float* __restrict__ dgc, const int* __restrict__ gidx,
    const float* __restrict__ bzc, float* __restrict__ out) {
  __shared__ float lds[2][HADN];        // 32 KiB -> 4 blocks x 8 waves = 32 w/CU
  const int tid = threadIdx.x;
  const int rr = tid >> 8;              // which of the block's 2 rows
  const long row = (long)blockIdx.x * 2;
  const int l = tid & 63;
  const int w = (tid >> 6) & 3;         // wave-in-row -> p-bits {10,11}
  const int base = (((l >> 2) & 1) << 2) | ((l & 1) << 5) | (((l >> 3) & 1) << 6)
                 | (((l >> 4) & 1) << 7) | (((l >> 1) & 1) << 8)
                 | (((l >> 5) & 1) << 9) | (w << 10);

  // ---- Stage 1: async DMA x -> LDS, wave-local region, pre-swizzled source.
  //      LDS[rr][q] = x_row[swz(q)] for q in [w*1024, w*1024+1024).
  const float* xr = x + (row + rr) * HADN;
#pragma unroll
  for (int k = 0; k < 4; ++k) {
    const int q = w * 1024 + k * 256 + l * 4;  // linear dest float index
    gload_lds16(xr + swz(q), &lds[rr][q]);
  }

  // Sign words + stage-3 tables (global, L2-resident): issue now, they drain
  // with the same per-wave vmcnt wait.
  const unsigned sw1 = D1sgn[base >> 5] >> (base & 4);
  const unsigned sw2 = D2sgn[base >> 5] >> (base & 4);
  const int o = tid * 4;                // 512 threads x 4 = all 2048 outputs
  const int4   gi = *(const int4*)(gidx + o);
  const float4 dg = *(const float4*)(dgc + o);
  const float4 bz = *(const float4*)(bzc + o);

  // Per-wave wait: this wave's DMA + table loads done. No block barrier.
  asm volatile("s_waitcnt vmcnt(0)" ::: "memory");
  __builtin_amdgcn_sched_barrier(0);

  // ---- Stage 2: 16 elems/lane of row rr; p-bits {0,1,3,4} thread-local,
  //      p-bit5 on lane-bit0 (DPP xor1), p-bit8 on lane-bit1 (DPP xor2) ----
  float r[16];
  float* L = &lds[rr][0];
#pragma unroll
  for (int g = 0; g < 4; ++g) {         // g bits -> p-bits {3,4}
    const int p = base | ((g & 1) << 3) | (((g >> 1) & 1) << 4);
    const float4 v = *(const float4*)(L + swz(p));
    r[g * 4 + 0] = v.x; r[g * 4 + 1] = v.y; r[g * 4 + 2] = v.z; r[g * 4 + 3] = v.w;
  }
  // D1 signs (input space), packed 1 word/lane.
#pragma unroll
  for (int e = 0; e < 16; ++e) {
    const int pos = (e & 3) | ((e & 12) << 1);   // e0,e1->bits0,1; e2,e3->bits3,4
    r[e] = __int_as_float(__float_as_int(r[e]) ^ ((sw1 >> pos) << 31));
  }
  // fwht #1: Hadamard on p-bits {1,3,4,5}: e-bits {1,2,3} + lane-bit0
  bfly<2>(r); bfly<4>(r); bfly<8>(r);
  dpp_bfly<0xB1>(r, (l & 1) != 0);
  // D2 signs (z-space), packed 1 word/lane.
#pragma unroll
  for (int e = 0; e < 16; ++e) {
    const int pos = (e & 3) | ((e & 12) << 1);
    r[e] = __int_as_float(__float_as_int(r[e]) ^ ((sw2 >> pos) << 31));
  }
  // fwht #2: Hadamard on p-bits {0,3,4,8}: e-bits {0,2,3} + lane-bit1
  bfly<1>(r); bfly<4>(r); bfly<8>(r);
  dpp_bfly<0x4E>(r, (l & 2) != 0);

  // Single LDS write (swizzled -> balanced 8 lanes per 4-bank group).
#pragma unroll
  for (int g = 0; g < 4; ++g) {
    const int p = base | ((g & 1) << 3) | (((g >> 1) & 1) << 4);
    const float4 v = make_float4(r[g * 4 + 0], r[g * 4 + 1], r[g * 4 + 2], r[g * 4 + 3]);
    *(float4*)(L + swz(p)) = v;
  }
  __syncthreads();  // only barrier: stage-2 of all waves visible to gather

  // ---- Stage 3: permuted gather, cos epilogue, coalesced CACHED stores.
  float* op = out + row * NFEAT;
  floatx4 res0;
  res0.x = 0.03125f * __builtin_amdgcn_cosf(fmaf(lds[0][gi.x], dg.x, bz.x));
  res0.y = 0.03125f * __builtin_amdgcn_cosf(fmaf(lds[0][gi.y], dg.y, bz.y));
  res0.z = 0.03125f * __builtin_amdgcn_cosf(fmaf(lds[0][gi.z], dg.z, bz.z));
  res0.w = 0.03125f * __builtin_amdgcn_cosf(fmaf(lds[0][gi.w], dg.w, bz.w));
  *(floatx4*)(op + o) = res0;
  floatx4 res1;
  res1.x = 0.03125f * __builtin_amdgcn_cosf(fmaf(lds[1][gi.x], dg.x, bz.x));
  res1.y = 0.03125f * __builtin_amdgcn_cosf(fmaf(lds[1][gi.y], dg.y, bz.y));
  res1.z = 0.03125f * __builtin_amdgcn_cosf(fmaf(lds[1][gi.z], dg.z, bz.z));
  res1.w = 0.03125f * __builtin_amdgcn_cosf(fmaf(lds[1][gi.w], dg.w, bz.w));
  *(floatx4*)(op + NFEAT + o) = res1;
}

extern "C" void kernel_launch(void* const* d_in, const int* in_sizes, int n_in,
                              void* d_out, int out_size, void* d_ws, size_t ws_size,
                              hipStream_t stream) {
  const float* x    = (const float*)d_in[0];
  const float* D1   = (const float*)d_in[1];
  const float* D2   = (const float*)d_in[2];
  const float* D3   = (const float*)d_in[3];
  const float* bias = (const float*)d_in[4];
  const int*   perm = (const int*)d_in[5];
  float* out = (float*)d_out;

  unsigned* D1sgn = (unsigned*)d_ws;        // 128 u32
  unsigned* D2sgn = D1sgn + 128;            // 128 u32
  float*    dgc   = (float*)(D2sgn + 128);  // 2048 f32
  int*      gidx  = (int*)(dgc + NFEAT);    // 2048 i32
  float*    bzc   = (float*)(gidx + NFEAT); // 2048 f32

  srf_setup<<<16, 256, 0, stream>>>(D1, D2, D3, perm, bias,
                                    D1sgn, D2sgn, dgc, gidx, bzc);
  srf_main<<<4096, 512, 0, stream>>>(x, D1sgn, D2sgn, dgc, gidx, bzc, out);
}